// Round 16
// baseline (187.875 us; speedup 1.0000x reference)
//
#include <hip/hip_runtime.h>

// 3x3 SAME conv + bias + ReLU, N=32, Cin=Cout=256, H=W=56, fp32 in/out.
// v16: v7 geometry with depth-2 counted-vmcnt pipeline:
//  - BM=128co x BN=128px, 512 thr / 8 waves, wave tile 64co x 32px
//    (4m x 2n frags, acc 32 regs), BK=64, 36 K-steps.
//  - THREE rotating LDS buffers (A 16KB + B 16KB each) = 96KB, 1 block/CU.
//  - Per step: [s_waitcnt vmcnt(4); s_barrier] (stage s retired, stage s+1
//    STAYS IN FLIGHT - no drain), issue stage s+2, then 12 ds_read_b128 +
//    16 MFMA with setprio. DMA gets ~2 steps (~1400cyc) of cover.
//  - v7-verified staging algebra: 8 lanes/row, chunk XOR (l&7)^(row&7),
//    wave-linear LDS dest; zero-page for halo; tap-inner K order;
//    x pre-transformed NHWC bf16; w repacked [co][tap*256+ci] bf16.

#define GLOBAL_AS __attribute__((address_space(1)))
#define LDS_AS __attribute__((address_space(3)))

typedef __attribute__((ext_vector_type(8))) short short8;
typedef __attribute__((ext_vector_type(4))) float f32x4;
typedef __attribute__((ext_vector_type(4))) unsigned int u32x4;

#define CIN   256
#define HWS   3136        // 56*56
#define PTOT  100352      // 32*3136
#define KTOT  2304        // CIN*9
#define WROWB 4608        // KTOT*2 bytes per weight row
#define ZPOFF 1179648     // 512B zero page
#define XTOFF 1310720     // x_t: PTOT*512 bytes
#define WSNEED (XTOFF + (size_t)PTOT * 512)

__device__ __forceinline__ unsigned short f2bf(float f) {
  unsigned u = __builtin_bit_cast(unsigned, f);
  return (unsigned short)((u + 0x7fffu + ((u >> 16) & 1u)) >> 16);  // RNE
}

// Weights OIHW fp32 -> bf16 [co][tap*256+ci]; also zero the zero-page.
__global__ void wcvt_kernel(const float* __restrict__ w, unsigned char* __restrict__ ws) {
  if (blockIdx.x == 0 && threadIdx.x < 128)
    ((unsigned*)(ws + ZPOFF))[threadIdx.x] = 0u;
  int o = blockIdx.x * 256 + threadIdx.x;
  int co = o / KTOT;
  int rr = o - co * KTOT;
  int tap = rr >> 8;
  int ci = rr & 255;
  ((unsigned short*)ws)[o] = f2bf(w[co * KTOT + ci * 9 + tap]);
}

// x NCHW fp32 -> x_t [pix_global][256ci] bf16 (NHWC), via LDS transpose.
__global__ __launch_bounds__(256) void xcvt_kernel(const float* __restrict__ x,
                                                   unsigned char* __restrict__ ws) {
  __shared__ float lt[64 * 257];
  const int pg0 = blockIdx.x * 64;       // 64-px tile, never crosses images
  const int n   = pg0 / HWS;
  const int pi0 = pg0 - n * HWS;
  const int t   = threadIdx.x;
  {
    const int px = t & 63;
    const int cg = t >> 6;               // 0..3 (wave-uniform)
    const float* xb = x + ((size_t)n * 256) * HWS + pi0 + px;
#pragma unroll 8
    for (int i = 0; i < 64; ++i) {
      const int c = i * 4 + cg;
      lt[px * 257 + c] = xb[(size_t)c * HWS];
    }
  }
  __syncthreads();
  {
    const int slot = t & 31;             // 16B slot = 8 channels (32 slots/row)
    const int pxw  = t >> 5;             // 0..7
    unsigned char* xt = ws + XTOFF;
#pragma unroll
    for (int i = 0; i < 8; ++i) {
      const int p = i * 8 + pxw;
      const float* r = &lt[p * 257 + slot * 8];
      u32x4 v;
#pragma unroll
      for (int j = 0; j < 4; ++j)
        v[j] = (unsigned)f2bf(r[2 * j]) | ((unsigned)f2bf(r[2 * j + 1]) << 16);
      *(u32x4*)(xt + (size_t)(pg0 + p) * 512 + slot * 16) = v;
    }
  }
}

__global__ __launch_bounds__(512, 2) void conv_kernel(
    const unsigned char* __restrict__ ws, const float* __restrict__ bias,
    float* __restrict__ out) {
  // LDS: 3 rotating buffers x (A 16KB + B 16KB)
  __shared__ __align__(16) unsigned char smem[98304];

  const unsigned char* wb = ws;
  const unsigned char* xt = ws + XTOFF;
  const unsigned char* zp = ws + ZPOFF;

  const int bid = blockIdx.x;
  const int sw  = (bid & 7) * 196 + (bid >> 3);  // XCD-chunked, bijective (1568=8*196)
  const int co0 = (sw & 1) * 128;
  const int p0  = (sw >> 1) * 128;               // global pixel base

  const int t    = threadIdx.x;
  const int lane = t & 63;
  const int wave = t >> 6;     // 0..7
  const int wm   = wave & 1;   // co 64-half
  const int wn   = wave >> 1;  // px 32-quarter (0..3)
  const int rl   = lane & 15;
  const int kq   = lane >> 4;
  const int l7   = lane & 7;
  const int l8   = lane >> 3;

  // pre-swizzled chunk offset within a 128B row (store & read use same XOR)
  const unsigned chanoff = (unsigned)((l7 * 16) ^ ((l8 & 7) << 4));

  // ---- staging lane precompute: op i covers row wave*16 + i*8 + l8 ----
  const unsigned char* aG[2];
  long long bG[2];
  int hB[2], wBp[2];
#pragma unroll
  for (int i = 0; i < 2; ++i) {
    const int row = wave * 16 + i * 8 + l8;       // 0..127
    aG[i] = wb + (size_t)(co0 + row) * WROWB + chanoff;
    const int pg = p0 + row;
    const int n  = pg / HWS;
    const int pi = pg - n * HWS;
    hB[i]  = pi / 56;
    wBp[i] = pi - hB[i] * 56;
    bG[i]  = (long long)pg * 512 + (long long)chanoff;
  }

  f32x4 acc[4][2];
  const f32x4 zero4 = {0.f, 0.f, 0.f, 0.f};
#pragma unroll
  for (int mi = 0; mi < 4; ++mi)
#pragma unroll
    for (int ni = 0; ni < 2; ++ni) acc[mi][ni] = zero4;

  // K-step s: cq = s/9, tap = s%9 (tap fastest -> x_t rows L2-hot)
  auto stage = [&](int s, unsigned bo) {
    const int cq  = s / 9;
    const int tap = s - cq * 9;
    const int kh  = tap / 3;
    const int dh  = kh - 1;
    const int dw  = (tap - kh * 3) - 1;
    const unsigned koffA = (unsigned)(tap * 512 + cq * 128);
    unsigned char* lb = smem + bo;
#pragma unroll
    for (int i = 0; i < 2; ++i)
      __builtin_amdgcn_global_load_lds(
          (const GLOBAL_AS unsigned int*)(aG[i] + koffA),
          (LDS_AS unsigned int*)(lb + (wave * 2 + i) * 1024), 16, 0, 0);
    const long long doff = (long long)(dh * 56 + dw) * 512 + cq * 128;
#pragma unroll
    for (int i = 0; i < 2; ++i) {
      const int hh  = hB[i] + dh;
      const int wwi = wBp[i] + dw;
      const bool ok = ((unsigned)hh < 56u) && ((unsigned)wwi < 56u);
      const unsigned char* g = ok ? (xt + bG[i] + doff) : (zp + chanoff);
      __builtin_amdgcn_global_load_lds(
          (const GLOBAL_AS unsigned int*)g,
          (LDS_AS unsigned int*)(lb + 16384 + (wave * 2 + i) * 1024), 16, 0, 0);
    }
  };

  // compute-phase per-lane offsets (128B rows; row&7 == rl&7 == l7)
  unsigned krd[2];
  krd[0] = (unsigned)((kq * 16) ^ (l7 << 4));
  krd[1] = (unsigned)((kq * 16 + 64) ^ (l7 << 4));
  unsigned offA[4], offB[2];
#pragma unroll
  for (int i = 0; i < 4; ++i)
    offA[i] = (unsigned)((wm * 64 + i * 16 + rl) * 128);
#pragma unroll
  for (int i = 0; i < 2; ++i)
    offB[i] = (unsigned)((wn * 32 + i * 16 + rl) * 128);

  auto compute = [&](unsigned bo) {
    const unsigned char* bA = smem + bo;
    const unsigned char* bB = bA + 16384;
#pragma unroll
    for (int ks = 0; ks < 2; ++ks) {
      short8 av[4], bv[2];
#pragma unroll
      for (int mi = 0; mi < 4; ++mi)
        av[mi] = *(const short8*)(bA + offA[mi] + krd[ks]);
#pragma unroll
      for (int ni = 0; ni < 2; ++ni)
        bv[ni] = *(const short8*)(bB + offB[ni] + krd[ks]);
      __builtin_amdgcn_s_setprio(1);
#pragma unroll
      for (int mi = 0; mi < 4; ++mi)
#pragma unroll
        for (int ni = 0; ni < 2; ++ni)
          acc[mi][ni] = __builtin_amdgcn_mfma_f32_16x16x32_bf16(
              av[mi], bv[ni], acc[mi][ni], 0, 0, 0);
      __builtin_amdgcn_s_setprio(0);
    }
  };

  // ---- prologue: 2 stages in flight ----
  stage(0, 0u);
  stage(1, 32768u);

  unsigned b0 = 0u, b1 = 32768u, b2 = 65536u;
#pragma unroll 1
  for (int s = 0; s < 36; ++s) {
    // entry: own stage-s ops retired (stage s+1 stays in flight), rendezvous
    if (s < 35) {
      asm volatile("s_waitcnt vmcnt(4)\n\ts_barrier" ::: "memory");
    } else {
      asm volatile("s_waitcnt vmcnt(0)\n\ts_barrier" ::: "memory");
    }
    if (s + 2 < 36) stage(s + 2, b2);
    compute(b0);
    const unsigned tmp = b0; b0 = b1; b1 = b2; b2 = tmp;
  }

  // ---- epilogue: bias + ReLU. C/D: col=lane&15, row=(lane>>4)*4+j ----
#pragma unroll
  for (int mi = 0; mi < 4; ++mi) {
    const int row = co0 + wm * 64 + mi * 16 + kq * 4;
    float br[4];
#pragma unroll
    for (int j = 0; j < 4; ++j) br[j] = bias[row + j];
#pragma unroll
    for (int ni = 0; ni < 2; ++ni) {
      const int pgb = p0 + wn * 32 + ni * 16;     // 16-span within one image
      const int n   = pgb / HWS;
      const int pib = pgb - n * HWS;
#pragma unroll
      for (int j = 0; j < 4; ++j) {
        float v = acc[mi][ni][j] + br[j];
        out[(size_t)(n * 256 + row + j) * HWS + pib + rl] = fmaxf(v, 0.f);
      }
    }
  }
}

// Correct-but-slow fallback if workspace is too small (not expected).
__global__ void naive_kernel(const float* __restrict__ x, const float* __restrict__ w,
                             const float* __restrict__ bias, float* __restrict__ out) {
  int idx = blockIdx.x * 256 + threadIdx.x;
  if (idx >= 32 * 256 * HWS) return;
  int n  = idx / (256 * HWS);
  int r  = idx - n * 256 * HWS;
  int co = r / HWS;
  int p  = r - co * HWS;
  int h = p / 56, ww = p - h * 56;
  float s = bias[co];
  const float* xb = x + (size_t)n * 256 * HWS;
  const float* wbp = w + (size_t)co * KTOT;
  for (int ci = 0; ci < 256; ++ci) {
    const float* xc = xb + (size_t)ci * HWS;
    const float* wc = wbp + ci * 9;
    for (int kh = 0; kh < 3; ++kh) {
      int hh = h + kh - 1;
      if ((unsigned)hh >= 56u) continue;
      for (int kw = 0; kw < 3; ++kw) {
        int w2 = ww + kw - 1;
        if ((unsigned)w2 >= 56u) continue;
        s += xc[hh * 56 + w2] * wc[kh * 3 + kw];
      }
    }
  }
  out[idx] = fmaxf(s, 0.f);
}

extern "C" void kernel_launch(void* const* d_in, const int* in_sizes, int n_in,
                              void* d_out, int out_size, void* d_ws, size_t ws_size,
                              hipStream_t stream) {
  const float* x    = (const float*)d_in[0];
  const float* w    = (const float*)d_in[1];
  const float* bias = (const float*)d_in[2];
  float* out        = (float*)d_out;

  if (ws_size < WSNEED) {
    hipLaunchKernelGGL(naive_kernel, dim3((32 * 256 * HWS + 255) / 256), dim3(256),
                       0, stream, x, w, bias, out);
    return;
  }
  unsigned char* ws = (unsigned char*)d_ws;
  hipLaunchKernelGGL(wcvt_kernel, dim3(2304), dim3(256), 0, stream, w, ws);
  hipLaunchKernelGGL(xcvt_kernel, dim3(PTOT / 64), dim3(256), 0, stream, x, ws);
  hipLaunchKernelGGL(conv_kernel, dim3(1568), dim3(512), 0, stream, ws, bias, out);
}

// Round 17
// 170.753 us; speedup vs baseline: 1.1003x; 1.1003x over previous
//
#include <hip/hip_runtime.h>

// 3x3 SAME conv + bias + ReLU, N=32, Cin=Cout=256, H=W=56, fp32 in/out.
// v17 = v7 structure with a near-zero-VALU inner loop:
//  - x_t stored PADDED: [n][58x58 granules][512B], halo zeroed by memset ->
//    no validity logic, no zero-page, every tap = base + constexpr delta.
//  - weights repacked K-step-major wf[co][s*64ch] -> A source offset = s*128
//    (13-bit immediate inside an 18-step unrolled body).
//  - compute ds_reads: per-lane base VGPRs + all-immediate offsets
//    (buf parity static in the unroll).
//  - BM=128co x BN=128px, 4 waves, wave tile 64x64, BK=64, 36 steps,
//    2-phase dbuf, one __syncthreads per step (v7-proven), 2 blocks/CU.

#define GLOBAL_AS __attribute__((address_space(1)))
#define LDS_AS __attribute__((address_space(3)))

typedef __attribute__((ext_vector_type(8))) short short8;
typedef __attribute__((ext_vector_type(4))) float f32x4;
typedef __attribute__((ext_vector_type(4))) unsigned int u32x4;

#define CIN   256
#define HWS   3136        // 56*56
#define PTOT  100352      // 32*3136
#define KTOT  2304        // CIN*9
#define IMGP  3364        // 58*58 padded granules per image
#define XTOFF 1310720     // x_t offset in ws
#define XTBYTES ((size_t)32 * IMGP * 512)
#define WSNEED (XTOFF + XTBYTES)

__device__ __forceinline__ unsigned short f2bf(float f) {
  unsigned u = __builtin_bit_cast(unsigned, f);
  return (unsigned short)((u + 0x7fffu + ((u >> 16) & 1u)) >> 16);  // RNE
}

// Weights OIHW fp32 -> bf16 K-step-major: wf[co][s*64 + c], s=cq*9+tap,
// element = w[co][cq*64+c][tap].
__global__ void wcvt_kernel(const float* __restrict__ w, unsigned char* __restrict__ ws) {
  int o = blockIdx.x * 256 + threadIdx.x;    // 0..589823
  int co = o / KTOT;
  int r  = o - co * KTOT;
  int s  = r >> 6;
  int c  = r & 63;
  int cq = s / 9;
  int tap = s - cq * 9;
  ((unsigned short*)ws)[o] = f2bf(w[co * KTOT + (cq * 64 + c) * 9 + tap]);
}

// x NCHW fp32 -> x_t padded [n][(h+1)*58+(w+1)][256ci] bf16 via LDS transpose.
__global__ __launch_bounds__(256) void xcvt_kernel(const float* __restrict__ x,
                                                   unsigned char* __restrict__ ws) {
  __shared__ float lt[64 * 257];
  const int pg0 = blockIdx.x * 64;       // 64-px tile, never crosses images
  const int n   = pg0 / HWS;
  const int pi0 = pg0 - n * HWS;
  const int t   = threadIdx.x;
  {
    const int px = t & 63;
    const int cg = t >> 6;               // 0..3 (wave-uniform)
    const float* xb = x + ((size_t)n * 256) * HWS + pi0 + px;
#pragma unroll 8
    for (int i = 0; i < 64; ++i) {
      const int c = i * 4 + cg;
      lt[px * 257 + c] = xb[(size_t)c * HWS];
    }
  }
  __syncthreads();
  {
    const int slot = t & 31;             // 16B slot = 8 channels (32 slots/row)
    const int pxw  = t >> 5;             // 0..7
    unsigned char* xt = ws + XTOFF;
#pragma unroll
    for (int i = 0; i < 8; ++i) {
      const int p  = i * 8 + pxw;
      const int pi = pi0 + p;
      const int h  = pi / 56;
      const int wcol = pi - h * 56;
      const size_t gran = (size_t)n * IMGP + (h + 1) * 58 + (wcol + 1);
      const float* r = &lt[p * 257 + slot * 8];
      u32x4 v;
#pragma unroll
      for (int j = 0; j < 4; ++j)
        v[j] = (unsigned)f2bf(r[2 * j]) | ((unsigned)f2bf(r[2 * j + 1]) << 16);
      *(u32x4*)(xt + gran * 512 + slot * 16) = v;
    }
  }
}

#define DTAP(tp) (((((tp) / 3) - 1) * 58 + ((tp) % 3) - 1) * 512)

__global__ __launch_bounds__(256, 2) void conv_kernel(
    const unsigned char* __restrict__ ws, const float* __restrict__ bias,
    float* __restrict__ out) {
  // LDS: buf{0,1} x (A 16KB + B 16KB)
  __shared__ __align__(16) unsigned char smem[65536];

  const unsigned char* wf = ws;
  const unsigned char* xt = ws + XTOFF;

  const int bid = blockIdx.x;
  const int sw  = (bid & 7) * 196 + (bid >> 3);  // XCD-chunked, bijective (1568=8*196)
  const int co0 = (sw & 1) * 128;
  const int p0  = (sw >> 1) * 128;               // global pixel base

  const int t    = threadIdx.x;
  const int lane = t & 63;
  const int wave = t >> 6;     // 0..3
  const int wm   = wave & 1;   // co 64-half
  const int wn   = wave >> 1;  // px 64-half
  const int rl   = lane & 15;
  const int kq   = lane >> 4;
  const int l7   = lane & 7;
  const int l8   = lane >> 3;

  // pre-swizzled chunk offset within a 128B row (store & read use same XOR)
  const unsigned chanoff = (unsigned)((l7 * 16) ^ ((l8 & 7) << 4));

  // ---- staging pointers (mutable, advanced once per 18-step body) ----
  const unsigned char* aP[4];
  const unsigned char* bP[4];
#pragma unroll
  for (int i = 0; i < 4; ++i) {
    const int row = wave * 32 + i * 8 + l8;       // 0..127
    aP[i] = wf + (size_t)(co0 + row) * 4608 + chanoff;
    const int pg = p0 + row;
    const int n  = pg / HWS;
    const int pi = pg - n * HWS;
    const int h  = pi / 56;
    const int wc = pi - h * 56;
    bP[i] = xt + ((size_t)n * IMGP + (h + 1) * 58 + (wc + 1)) * 512 + chanoff;
  }
  const unsigned ldsA = (unsigned)(wave * 4096);  // + i*1024 per op

  // ---- compute-phase per-lane base addresses (all reads imm-offset) ----
  const unsigned krd0 = (unsigned)((kq * 16) ^ (l7 << 4));
  const unsigned krd1 = (unsigned)((kq * 16 + 64) ^ (l7 << 4));
  const unsigned char* pA0 = smem + (wm * 64 + rl) * 128 + krd0;
  const unsigned char* pA1 = smem + (wm * 64 + rl) * 128 + krd1;
  const unsigned char* pB0 = smem + 16384 + (wn * 64 + rl) * 128 + krd0;
  const unsigned char* pB1 = smem + 16384 + (wn * 64 + rl) * 128 + krd1;

  f32x4 acc[4][4];
  const f32x4 zero4 = {0.f, 0.f, 0.f, 0.f};
#pragma unroll
  for (int mi = 0; mi < 4; ++mi)
#pragma unroll
    for (int ni = 0; ni < 4; ++ni) acc[mi][ni] = zero4;

#define STAGE(DB, AOFF, BD)                                                   \
  {                                                                           \
    _Pragma("unroll") for (int i_ = 0; i_ < 4; ++i_)                          \
        __builtin_amdgcn_global_load_lds(                                     \
            (const GLOBAL_AS unsigned int*)(aP[i_] + (AOFF)),                 \
            (LDS_AS unsigned int*)(smem + (DB)*32768 + ldsA + i_ * 1024),     \
            16, 0, 0);                                                        \
    _Pragma("unroll") for (int i_ = 0; i_ < 4; ++i_)                          \
        __builtin_amdgcn_global_load_lds(                                     \
            (const GLOBAL_AS unsigned int*)(bP[i_] + (BD)),                   \
            (LDS_AS unsigned int*)(smem + (DB)*32768 + 16384 + ldsA +         \
                                   i_ * 1024),                                \
            16, 0, 0);                                                        \
  }

#define COMP(BUF)                                                             \
  {                                                                           \
    short8 av[4], bv[4];                                                      \
    _Pragma("unroll") for (int mi = 0; mi < 4; ++mi)                          \
        av[mi] = *(const short8*)(pA0 + (BUF)*32768 + mi * 2048);             \
    _Pragma("unroll") for (int ni = 0; ni < 4; ++ni)                          \
        bv[ni] = *(const short8*)(pB0 + (BUF)*32768 + ni * 2048);             \
    _Pragma("unroll") for (int mi = 0; mi < 4; ++mi)                          \
      _Pragma("unroll") for (int ni = 0; ni < 4; ++ni)                        \
          acc[mi][ni] = __builtin_amdgcn_mfma_f32_16x16x32_bf16(              \
              av[mi], bv[ni], acc[mi][ni], 0, 0, 0);                          \
    _Pragma("unroll") for (int mi = 0; mi < 4; ++mi)                          \
        av[mi] = *(const short8*)(pA1 + (BUF)*32768 + mi * 2048);             \
    _Pragma("unroll") for (int ni = 0; ni < 4; ++ni)                          \
        bv[ni] = *(const short8*)(pB1 + (BUF)*32768 + ni * 2048);             \
    _Pragma("unroll") for (int mi = 0; mi < 4; ++mi)                          \
      _Pragma("unroll") for (int ni = 0; ni < 4; ++ni)                        \
          acc[mi][ni] = __builtin_amdgcn_mfma_f32_16x16x32_bf16(              \
              av[mi], bv[ni], acc[mi][ni], 0, 0, 0);                          \
  }

// step J (0..16) of an 18-step body: stage s=J+1, compute s=J, sync
#define STEPJ(J)                                                              \
  STAGE(((J) + 1) & 1, ((J) + 1) * 128,                                       \
        DTAP((((J) + 1) % 9)) + (((J) + 1) / 9) * 128);                       \
  COMP((J)&1);                                                                \
  __syncthreads();

  // ---- prologue: stage s=0 into buf0 ----
  STAGE(0, 0, DTAP(0))
  __syncthreads();

#pragma unroll 1
  for (int gg = 0; gg < 2; ++gg) {
    STEPJ(0) STEPJ(1) STEPJ(2) STEPJ(3) STEPJ(4) STEPJ(5) STEPJ(6) STEPJ(7)
    STEPJ(8) STEPJ(9) STEPJ(10) STEPJ(11) STEPJ(12) STEPJ(13) STEPJ(14)
    STEPJ(15) STEPJ(16)
    // step 17: stage next body's s=0 (after pointer advance), compute, sync
    if (gg == 0) {
#pragma unroll
      for (int i = 0; i < 4; ++i) {
        aP[i] += 2304;   // 18 steps * 128B
        bP[i] += 256;    // 2 channel-chunks * 128B
      }
      STAGE(0, 0, DTAP(0))
    }
    COMP(1)
    __syncthreads();
  }
#undef STEPJ
#undef COMP
#undef STAGE

  // ---- epilogue: bias + ReLU. C/D: col=lane&15, row=(lane>>4)*4+j ----
#pragma unroll
  for (int mi = 0; mi < 4; ++mi) {
    const int row = co0 + wm * 64 + mi * 16 + kq * 4;
    float br[4];
#pragma unroll
    for (int j = 0; j < 4; ++j) br[j] = bias[row + j];
#pragma unroll
    for (int ni = 0; ni < 4; ++ni) {
      const int pgb = p0 + wn * 64 + ni * 16;     // 16-span within one image
      const int n   = pgb / HWS;
      const int pib = pgb - n * HWS;
#pragma unroll
      for (int j = 0; j < 4; ++j) {
        float v = acc[mi][ni][j] + br[j];
        out[(size_t)(n * 256 + row + j) * HWS + pib + rl] = fmaxf(v, 0.f);
      }
    }
  }
}

// Correct-but-slow fallback if workspace is too small (not expected).
__global__ void naive_kernel(const float* __restrict__ x, const float* __restrict__ w,
                             const float* __restrict__ bias, float* __restrict__ out) {
  int idx = blockIdx.x * 256 + threadIdx.x;
  if (idx >= 32 * 256 * HWS) return;
  int n  = idx / (256 * HWS);
  int r  = idx - n * 256 * HWS;
  int co = r / HWS;
  int p  = r - co * HWS;
  int h = p / 56, ww = p - h * 56;
  float s = bias[co];
  const float* xb = x + (size_t)n * 256 * HWS;
  const float* wbp = w + (size_t)co * KTOT;
  for (int ci = 0; ci < 256; ++ci) {
    const float* xc = xb + (size_t)ci * HWS;
    const float* wc = wbp + ci * 9;
    for (int kh = 0; kh < 3; ++kh) {
      int hh = h + kh - 1;
      if ((unsigned)hh >= 56u) continue;
      for (int kw = 0; kw < 3; ++kw) {
        int w2 = ww + kw - 1;
        if ((unsigned)w2 >= 56u) continue;
        s += xc[hh * 56 + w2] * wc[kh * 3 + kw];
      }
    }
  }
  out[idx] = fmaxf(s, 0.f);
}

extern "C" void kernel_launch(void* const* d_in, const int* in_sizes, int n_in,
                              void* d_out, int out_size, void* d_ws, size_t ws_size,
                              hipStream_t stream) {
  const float* x    = (const float*)d_in[0];
  const float* w    = (const float*)d_in[1];
  const float* bias = (const float*)d_in[2];
  float* out        = (float*)d_out;

  if (ws_size < WSNEED) {
    hipLaunchKernelGGL(naive_kernel, dim3((32 * 256 * HWS + 255) / 256), dim3(256),
                       0, stream, x, w, bias, out);
    return;
  }
  unsigned char* ws = (unsigned char*)d_ws;
  hipMemsetAsync(ws + XTOFF, 0, XTBYTES, stream);   // zero the halo (and all)
  hipLaunchKernelGGL(wcvt_kernel, dim3(2304), dim3(256), 0, stream, w, ws);
  hipLaunchKernelGGL(xcvt_kernel, dim3(PTOT / 64), dim3(256), 0, stream, x, ws);
  hipLaunchKernelGGL(conv_kernel, dim3(1568), dim3(256), 0, stream, ws, bias, out);
}